// Round 1
// baseline (46863.312 us; speedup 1.0000x reference)
//
#include <hip/hip_runtime.h>
#include <cmath>
#include <vector>

#define B_SZ 64
#define SEQ 512
#define IN_D 512
#define HID 1024
#define MEM_DIM 8
#define ORD 256
#define MFLAT (MEM_DIM*ORD)          // 2048
#define KTOT (IN_D + HID + MFLAT)    // 3584

// ---------------- host-side expm (double, scaling & squaring) ----------------
static void matmul_d(const double* A, const double* B, double* C, int n) {
  for (int i = 0; i < n; ++i) {
    double* Ci = C + (size_t)i * n;
    for (int j = 0; j < n; ++j) Ci[j] = 0.0;
    const double* Ai = A + (size_t)i * n;
    for (int k = 0; k < n; ++k) {
      double a = Ai[k];
      const double* Bk = B + (size_t)k * n;
      for (int j = 0; j < n; ++j) Ci[j] += a * Bk[j];
    }
  }
}

// Computes ZOH-discretized Legendre system: AdT[o*256+p] = Ad[p][o] (transposed), Bd[p].
static void compute_AB_host(float* AdT, float* Bd) {
  const int q = ORD, n = ORD + 1;
  const double theta = 512.0;
  std::vector<double> M((size_t)n * n, 0.0);
  for (int i = 0; i < q; ++i) {
    double r = (2.0 * i + 1.0) / theta;
    for (int j = 0; j < q; ++j) {
      double v = (i < j) ? -1.0 : ((((i - j) % 2) == 1) ? 1.0 : -1.0);
      M[(size_t)i * n + j] = v * r;
    }
    M[(size_t)i * n + q] = (((i % 2) == 0) ? 1.0 : -1.0) * r;
  }
  // 1-norm and scaling
  double norm = 0.0;
  for (int j = 0; j < n; ++j) {
    double s = 0.0;
    for (int i = 0; i < n; ++i) s += fabs(M[(size_t)i * n + j]);
    if (s > norm) norm = s;
  }
  int s = 0;
  while (norm > 0.25) { norm *= 0.5; ++s; }
  double sc = ldexp(1.0, -s);
  for (size_t i = 0; i < M.size(); ++i) M[i] *= sc;
  // Taylor series
  std::vector<double> E((size_t)n * n, 0.0), P = M, T((size_t)n * n);
  for (int i = 0; i < n; ++i) E[(size_t)i * n + i] = 1.0;
  for (size_t i = 0; i < M.size(); ++i) E[i] += M[i];
  for (int k = 2; k <= 30; ++k) {
    matmul_d(P.data(), M.data(), T.data(), n);
    double inv = 1.0 / (double)k, mx = 0.0;
    for (size_t i = 0; i < T.size(); ++i) {
      T[i] *= inv;
      double a = fabs(T[i]);
      if (a > mx) mx = a;
    }
    P.swap(T);
    for (size_t i = 0; i < M.size(); ++i) E[i] += P[i];
    if (mx < 1e-19) break;
  }
  // Squarings
  for (int it = 0; it < s; ++it) {
    matmul_d(E.data(), E.data(), T.data(), n);
    E.swap(T);
  }
  for (int p = 0; p < q; ++p) {
    for (int o = 0; o < q; ++o) AdT[(size_t)o * q + p] = (float)E[(size_t)p * n + o];
    Bd[p] = (float)E[(size_t)p * n + q];
  }
}

// ---------------- kernel 1: u + m update ----------------
// grid 256 = (b:64) x (d-pair:4); block 256 threads.
__global__ __launch_bounds__(256) void lmu_step_m(
    const float* __restrict__ x, const float* __restrict__ Ex,
    const float* __restrict__ Eh, const float* __restrict__ Em,
    const float* __restrict__ AdT, const float* __restrict__ Bd,
    const float* __restrict__ hprev, const float* __restrict__ mprev,
    float* __restrict__ mnext, int t)
{
  __shared__ float2 m_l[ORD];
  __shared__ float red0[256], red1[256];
  __shared__ float u_sh[2];
  int tid = threadIdx.x;
  int b = blockIdx.x >> 2;
  int dd = blockIdx.x & 3;
  int d0 = dd * 2, d1 = d0 + 1;
  const float* xrow = x + ((size_t)b * SEQ + t) * IN_D;
  const float* hrow = hprev + (size_t)b * HID;
  const float* mrow = mprev + (size_t)b * MFLAT;

  // stage the two m rows (interleaved float2)
  {
    float a0 = mrow[d0 * ORD + tid];
    float a1 = mrow[d1 * ORD + tid];
    m_l[tid] = make_float2(a0, a1);
  }
  // u = Ex x_t + Eh h_{t-1} + Em m_{t-1}  (K = 3584 dot, both d's)
  float p0 = 0.f, p1 = 0.f;
  for (int k = tid; k < KTOT; k += 256) {
    float sv, e0, e1;
    if (k < IN_D) {
      sv = xrow[k];
      e0 = Ex[(size_t)d0 * IN_D + k]; e1 = Ex[(size_t)d1 * IN_D + k];
    } else if (k < IN_D + HID) {
      int kk = k - IN_D;
      sv = hrow[kk];
      e0 = Eh[(size_t)d0 * HID + kk]; e1 = Eh[(size_t)d1 * HID + kk];
    } else {
      int kk = k - IN_D - HID;
      sv = mrow[kk];
      e0 = Em[(size_t)d0 * MFLAT + kk]; e1 = Em[(size_t)d1 * MFLAT + kk];
    }
    p0 = fmaf(sv, e0, p0);
    p1 = fmaf(sv, e1, p1);
  }
  red0[tid] = p0; red1[tid] = p1;
  __syncthreads();
  for (int off = 128; off > 0; off >>= 1) {
    if (tid < off) { red0[tid] += red0[tid + off]; red1[tid] += red1[tid + off]; }
    __syncthreads();
  }
  if (tid == 0) { u_sh[0] = red0[0]; u_sh[1] = red1[0]; }
  __syncthreads();
  float u0 = u_sh[0], u1 = u_sh[1];

  // m_t[d, p] = sum_o Ad[p,o] m[d,o] + u[d]*Bv[p];  p = tid
  int p = tid;
  float bv = Bd[p];
  float acc0 = u0 * bv, acc1 = u1 * bv;
  #pragma unroll 8
  for (int o = 0; o < ORD; ++o) {
    float a = AdT[(size_t)o * ORD + p];   // coalesced across p
    float2 mv = m_l[o];                   // broadcast
    acc0 = fmaf(a, mv.x, acc0);
    acc1 = fmaf(a, mv.y, acc1);
  }
  float* mout = mnext + (size_t)b * MFLAT;
  mout[d0 * ORD + p] = acc0;
  mout[d1 * ORD + p] = acc1;
}

// ---------------- kernel 2: h update ----------------
// grid 64 = (beta:2) x (iota:32); block 512 threads; tile 32b x 32i, thread = 2b x 1i.
// pre[b,i] = Wx.x_t + Wh.h_{t-1} + Wm.m_t ; h = tanh(pre)
__global__ __launch_bounds__(512) void lmu_step_h(
    const float* __restrict__ x, const float* __restrict__ Wx,
    const float* __restrict__ Wh, const float* __restrict__ Wm,
    const float* __restrict__ hprev, const float* __restrict__ mnew,
    float* __restrict__ hnext, float* __restrict__ out, int t)
{
  __shared__ float lds[32 * 512];   // 64 KiB: 32 batch rows x 512-float K-chunk
  int tid = threadIdx.x;
  int beta = blockIdx.x & 1;
  int iota = blockIdx.x >> 1;
  int bl2 = tid & 15;
  int iw = tid >> 4;            // 0..31
  int b0l = bl2 * 2, b1l = b0l + 1;
  int i = iota * 32 + iw;
  int sw = bl2 & 7;             // == (b0l>>1)&7 == (b1l>>1)&7
  float acc0 = 0.f, acc1 = 0.f;
  float4* lds4 = (float4*)lds;

  for (int c = 0; c < 7; ++c) {   // 7 K-chunks of 512: [x | h h | m m m m]
    __syncthreads();              // WAR: previous chunk's reads complete
    for (int g = tid; g < 4096; g += 512) {
      int bl = g >> 7;            // 0..31 local batch row
      int kk = g & 127;           // float4 granule in row
      int bg = beta * 32 + bl;
      const float4* s4;
      if (c == 0)
        s4 = (const float4*)(x + ((size_t)bg * SEQ + t) * IN_D) + kk;
      else if (c <= 2)
        s4 = (const float4*)(hprev + (size_t)bg * HID + (size_t)(c - 1) * 512) + kk;
      else
        s4 = (const float4*)(mnew + (size_t)bg * MFLAT + (size_t)(c - 3) * 512) + kk;
      lds4[bl * 128 + (kk ^ ((bl >> 1) & 7))] = *s4;   // XOR swizzle -> 2-way (free) on reads
    }
    __syncthreads();
    const float* wrow;
    if (c == 0)      wrow = Wx + (size_t)i * IN_D;
    else if (c <= 2) wrow = Wh + (size_t)i * HID + (size_t)(c - 1) * 512;
    else             wrow = Wm + (size_t)i * MFLAT + (size_t)(c - 3) * 512;
    const float4* w4 = (const float4*)wrow;
    const float4* l0 = lds4 + b0l * 128;
    const float4* l1 = lds4 + b1l * 128;
    #pragma unroll 4
    for (int kk = 0; kk < 128; ++kk) {
      float4 w = w4[kk];
      float4 s0 = l0[kk ^ sw];
      float4 s1 = l1[kk ^ sw];
      acc0 += w.x * s0.x; acc0 += w.y * s0.y; acc0 += w.z * s0.z; acc0 += w.w * s0.w;
      acc1 += w.x * s1.x; acc1 += w.y * s1.y; acc1 += w.z * s1.z; acc1 += w.w * s1.w;
    }
  }
  int bg0 = beta * 32 + b0l;
  int bg1 = bg0 + 1;
  float h0 = tanhf(acc0), h1 = tanhf(acc1);
  hnext[(size_t)bg0 * HID + i] = h0;
  hnext[(size_t)bg1 * HID + i] = h1;
  out[((size_t)bg0 * SEQ + t) * HID + i] = h0;
  out[((size_t)bg1 * SEQ + t) * HID + i] = h1;
}

// ---------------- launch ----------------
extern "C" void kernel_launch(void* const* d_in, const int* in_sizes, int n_in,
                              void* d_out, int out_size, void* d_ws, size_t ws_size,
                              hipStream_t stream) {
  const float* x  = (const float*)d_in[0];
  const float* Ex = (const float*)d_in[1];
  const float* Eh = (const float*)d_in[2];
  const float* Em = (const float*)d_in[3];
  const float* Wx = (const float*)d_in[4];
  const float* Wh = (const float*)d_in[5];
  const float* Wm = (const float*)d_in[6];
  float* out = (float*)d_out;
  float* ws = (float*)d_ws;

  // ws layout (floats): AdT[65536] | Bd[256] | pad | hbuf[2][64*1024] | mbuf[2][64*2048]
  float* dAdT = ws;
  float* dBd  = ws + 65536;
  float* hbuf0 = ws + 66048;
  float* hbuf1 = hbuf0 + B_SZ * HID;
  float* mbuf0 = ws + 197120;
  float* mbuf1 = mbuf0 + B_SZ * MFLAT;
  float* hb[2] = { hbuf0, hbuf1 };
  float* mb[2] = { mbuf0, mbuf1 };

  // Host expm every call (deterministic); static buffers persist for graph replay.
  static float h_AdT[ORD * ORD];
  static float h_Bd[ORD];
  compute_AB_host(h_AdT, h_Bd);
  hipMemcpyAsync(dAdT, h_AdT, sizeof(h_AdT), hipMemcpyHostToDevice, stream);
  hipMemcpyAsync(dBd,  h_Bd,  sizeof(h_Bd),  hipMemcpyHostToDevice, stream);

  hipMemsetAsync(hb[0], 0, (size_t)B_SZ * HID * sizeof(float), stream);
  hipMemsetAsync(mb[0], 0, (size_t)B_SZ * MFLAT * sizeof(float), stream);

  for (int t = 0; t < SEQ; ++t) {
    int cur = t & 1, nxt = cur ^ 1;
    lmu_step_m<<<dim3(256), dim3(256), 0, stream>>>(
        x, Ex, Eh, Em, dAdT, dBd, hb[cur], mb[cur], mb[nxt], t);
    lmu_step_h<<<dim3(64), dim3(512), 0, stream>>>(
        x, Wx, Wh, Wm, hb[cur], mb[nxt], hb[nxt], out, t);
  }
}